// Round 1
// baseline (1328.940 us; speedup 1.0000x reference)
//
#include <hip/hip_runtime.h>
#include <hip/hip_bf16.h>

// Problem constants (from reference source)
#define REGION_R0 42033
#define REGION_R1 44630
#define CH 64

// -------------------------------------------------------------------------
// K1: region GEMM + blend.
// region_ent[i][c] = 0.8*emb[R0+i][c] + 0.2 * sum_k W[i][k] * emb[R0+k][c]
// Block = 256 threads = 4 waves; each wave computes 8 output rows, lane = channel.
// -------------------------------------------------------------------------
__global__ void region_gemm_kernel(const float* __restrict__ emb,
                                   const float* __restrict__ W,
                                   float* __restrict__ region_ent,
                                   int RN) {
    const int wave = threadIdx.x >> 6;       // 0..3
    const int c    = threadIdx.x & 63;       // channel
    const int base = blockIdx.x * 32 + wave * 8;
    if (base >= RN) return;

    float acc[8];
#pragma unroll
    for (int r = 0; r < 8; ++r) acc[r] = 0.0f;

    // row indices (clamped so the unrolled loop stays branch-free)
    int rows[8];
#pragma unroll
    for (int r = 0; r < 8; ++r) {
        int i = base + r;
        rows[r] = (i < RN) ? i : (RN - 1);
    }

    for (int k = 0; k < RN; ++k) {
        const float e = emb[(size_t)(REGION_R0 + k) * CH + c];
#pragma unroll
        for (int r = 0; r < 8; ++r) {
            acc[r] += W[(size_t)rows[r] * RN + k] * e;
        }
    }

#pragma unroll
    for (int r = 0; r < 8; ++r) {
        const int i = base + r;
        if (i < RN) {
            const float orig = emb[(size_t)(REGION_R0 + i) * CH + c];
            region_ent[(size_t)i * CH + c] = 0.8f * orig + 0.2f * acc[r];
        }
    }
}

__device__ __forceinline__ float ent_val(const float* __restrict__ emb,
                                         const float* __restrict__ region_ent,
                                         int row, int c) {
    if (row >= REGION_R0 && row < REGION_R1) {
        return region_ent[(size_t)(row - REGION_R0) * CH + c];
    }
    return emb[(size_t)row * CH + c];
}

// -------------------------------------------------------------------------
// K2: KG aggregate scatter. One thread per (edge, channel).
// -------------------------------------------------------------------------
__global__ void kg_agg_kernel(const float* __restrict__ emb,
                              const float* __restrict__ region_ent,
                              const int* __restrict__ edge_index,
                              const int* __restrict__ edge_type,
                              const float* __restrict__ weight,
                              float* __restrict__ out_ent,
                              float* __restrict__ counts,
                              int E, int n_rel) {
    const int gid = blockIdx.x * blockDim.x + threadIdx.x;
    const int e = gid >> 6;
    if (e >= E) return;
    const int c = gid & 63;

    const int h  = edge_index[e];
    const int t  = edge_index[(size_t)E + e];
    int r = edge_type[e] - 1;
    if (r < 0) r += n_rel;           // python (x-1) % n_rel for x in [0, n_rel)

    const float ev = ent_val(emb, region_ent, t, c);
    const float v  = ev * weight[(size_t)r * CH + c];
    atomicAdd(out_ent + (size_t)h * CH + c, v);
    if (c == 0) atomicAdd(counts + h, 1.0f);
}

// -------------------------------------------------------------------------
// K3: user aggregate scatter. One thread per (nnz, channel).
// -------------------------------------------------------------------------
__global__ void user_agg_kernel(const float* __restrict__ emb,
                                const float* __restrict__ region_ent,
                                const int* __restrict__ irows,
                                const int* __restrict__ icols,
                                const float* __restrict__ ivals,
                                float* __restrict__ out_user,
                                int NNZ) {
    const int gid = blockIdx.x * blockDim.x + threadIdx.x;
    const int i = gid >> 6;
    if (i >= NNZ) return;
    const int c = gid & 63;

    const int row = irows[i];
    const int col = icols[i];
    const float v = ivals[i];
    const float ev = ent_val(emb, region_ent, col, c);
    atomicAdd(out_user + (size_t)row * CH + c, v * ev);
}

// -------------------------------------------------------------------------
// K4: finalize entity_agg = sums / max(counts, 1)
// -------------------------------------------------------------------------
__global__ void finalize_kernel(float* __restrict__ out_ent,
                                const float* __restrict__ counts,
                                int n_entities) {
    const int gid = blockIdx.x * blockDim.x + threadIdx.x;
    if (gid >= n_entities * CH) return;
    const float cnt = fmaxf(counts[gid >> 6], 1.0f);
    out_ent[gid] = out_ent[gid] / cnt;
}

extern "C" void kernel_launch(void* const* d_in, const int* in_sizes, int n_in,
                              void* d_out, int out_size, void* d_ws, size_t ws_size,
                              hipStream_t stream) {
    const float* entity_emb = (const float*)d_in[0];
    // d_in[1] = user_emb : unused by the reference outputs
    const int*   edge_index = (const int*)d_in[2];
    const int*   edge_type  = (const int*)d_in[3];
    const int*   irows      = (const int*)d_in[4];
    const int*   icols      = (const int*)d_in[5];
    const float* ivals      = (const float*)d_in[6];
    const float* Wreg       = (const float*)d_in[7];
    const float* weight     = (const float*)d_in[8];

    const int n_entities = in_sizes[0] / CH;
    const int E          = in_sizes[3];
    const int NNZ        = in_sizes[4];
    const int n_rel      = in_sizes[8] / CH;
    const int RN         = REGION_R1 - REGION_R0;   // 2597

    float* out_ent  = (float*)d_out;
    float* out_user = out_ent + (size_t)n_entities * CH;

    // workspace layout: region_ent [RN*CH] | counts [n_entities]
    float* region_ent = (float*)d_ws;
    float* counts     = region_ent + (size_t)RN * CH;

    // zero the accumulators (harness poisons with 0xAA, does not re-poison)
    hipMemsetAsync(d_out, 0, (size_t)out_size * sizeof(float), stream);
    hipMemsetAsync(counts, 0, (size_t)n_entities * sizeof(float), stream);

    // K1: region GEMM (82 blocks x 256)
    region_gemm_kernel<<<(RN + 31) / 32, 256, 0, stream>>>(
        entity_emb, Wreg, region_ent, RN);

    // K2: KG scatter (E*64 threads)
    {
        const long long tot = (long long)E * CH;
        const int grid = (int)((tot + 255) / 256);
        kg_agg_kernel<<<grid, 256, 0, stream>>>(
            entity_emb, region_ent, edge_index, edge_type, weight,
            out_ent, counts, E, n_rel);
    }

    // K3: user scatter (NNZ*64 threads)
    {
        const long long tot = (long long)NNZ * CH;
        const int grid = (int)((tot + 255) / 256);
        user_agg_kernel<<<grid, 256, 0, stream>>>(
            entity_emb, region_ent, irows, icols, ivals, out_user, NNZ);
    }

    // K4: finalize mean
    {
        const long long tot = (long long)n_entities * CH;
        const int grid = (int)((tot + 255) / 256);
        finalize_kernel<<<grid, 256, 0, stream>>>(out_ent, counts, n_entities);
    }
}